// Round 16
// baseline (227.452 us; speedup 1.0000x reference)
//
#include <hip/hip_runtime.h>
#include <stdint.h>

#define N_S 30000
#define N_G 3000
#define DD  128
#define KK  16
#define NE  (N_G * KK)
#define NC  16            // cells per axis
#define CELLS (NC * NC * NC)
#define CH  3.75f         // cell size (60/16), exactly representable
#define CAP 16            // slots per cell; overflow list keeps exactness
#define SURV 448          // survivor buffer capacity (covers R=2 medium path)

#define FILL_BLOCKS 118   // ceil(30000/256)
#define PACK_BLOCKS 384   // 768 weight-row tasks, 2 per block
#define KNN_BLOCKS  3000  // one 64-thr block per graph node
#define NBS16 1875        // 30000/16 pre tiles (s)
#define NBG16 188         // ceil(3000/16) pre tiles (g)
#define PRE_TILES (NBS16 + NBG16)   // 2063
#define NBS 469           // ceil(30000/64) post tiles (s)
#define NBG 47            // ceil(3000/64) post tiles (g)
#define NTILE (NBS + NBG) // 516

using v8s = __attribute__((ext_vector_type(8))) short;   // 8 bf16 (4 VGPRs)
using v4f = __attribute__((ext_vector_type(4))) float;   // MFMA accumulator

__device__ __forceinline__ float bf2f(unsigned short u) {
    union { unsigned int i; float f; } v; v.i = ((unsigned int)u) << 16; return v.f;
}
__device__ __forceinline__ unsigned short f2bf(float f) {
    union { float f; unsigned int i; } v; v.f = f;
    unsigned int x = v.i;
    return (unsigned short)((x + 0x7fffu + ((x >> 16) & 1u)) >> 16);
}
__device__ __forceinline__ float ldIn(const void* p, int i, int bf) {
    return bf ? bf2f(((const unsigned short*)p)[i]) : ((const float*)p)[i];
}
__device__ __forceinline__ void stOut(void* p, int i, float v, int bf) {
    if (bf) ((unsigned short*)p)[i] = f2bf(v);
    else    ((float*)p)[i] = v;
}
__device__ __forceinline__ int cellOf(float x) {
    int c = (int)(x * (1.0f / CH));
    if (c < 0) c = 0; if (c > NC - 1) c = NC - 1;
    return c;
}

// Inline dtype probe: 16 u32 words of pos_g; bf16 low-halves in [0.25,64) put
// (w>>8)&0xFF in [0x3E,0x42]; f32 mantissa bytes ~uniform (0-1 votes of 16).
__device__ __forceinline__ int detectFlag(const void* pos_g) {
    const unsigned int* w = (const unsigned int*)pos_g;
    int votes = 0;
#pragma unroll
    for (int i = 0; i < 16; ++i) {
        const unsigned int b = (w[i] >> 8) & 0xFFu;
        votes += (b >= 0x3Eu && b <= 0x42u) ? 1 : 0;
    }
    return votes >= 8;
}

// Exact global ranks for n survivors in LDS (lex (key,sid) order; sid unique).
// Broadcast j-loop: skey[j]/ssid[j] reads are wave-uniform -> no conflicts.
__device__ __forceinline__ void rank_emit(int g, int n,
                                          const double* __restrict__ skey,
                                          const int* __restrict__ ssid,
                                          int* __restrict__ idx_out,
                                          float* __restrict__ w_out)
{
    const int t = threadIdx.x;
    double ki[7]; int si[7]; int rk[7]; int nv = 0;
    for (int i = t; i < n && nv < 7; i += 64) {
        ki[nv] = skey[i]; si[nv] = ssid[i]; rk[nv] = 0; ++nv;
    }
    for (int j = 0; j < n; ++j) {
        const double kj = skey[j]; const int sj = ssid[j];
#pragma unroll
        for (int q = 0; q < 7; ++q)
            if (q < nv)
                rk[q] += ((kj < ki[q]) || (kj == ki[q] && sj < si[q])) ? 1 : 0;
    }
#pragma unroll
    for (int q = 0; q < 7; ++q) {
        if (q < nv && rk[q] < KK) {
            idx_out[g * KK + rk[q]] = si[q];
            w_out[g * KK + rk[q]] = expf((float)(-ki[q]) * (1.0f / 12.5f));
        }
    }
}

// ---------------------------------------------------------------------------
// FAST exact kNN (R=1 cube, ~99.8% of nodes). Threshold m known a priori
// (min distance to the 3x3x3 region boundary, >= 3.75). Survivors = exactly
// {d2 < m2eff}; if count >= 16, true top-16 = survivors with lex-rank < 16.
// ---------------------------------------------------------------------------
__device__ bool knn_fast(int g, int bf, const void* pos_g,
                         const int* __restrict__ ccnt,
                         const float4* __restrict__ scell,
                         const float4* __restrict__ ovf, int novf,
                         int* __restrict__ idx_out, float* __restrict__ w_out,
                         double* skey, int* ssid)
{
    const int t = threadIdx.x;   // 0..63

    const float gxf = ldIn(pos_g, 3 * g + 0, bf);
    const float gyf = ldIn(pos_g, 3 * g + 1, bf);
    const float gzf = ldIn(pos_g, 3 * g + 2, bf);
    const double gx = (double)gxf, gy = (double)gyf, gz = (double)gzf;
    const int cx = cellOf(gxf), cy = cellOf(gyf), cz = cellOf(gzf);

    double m = 1e300;
    if (cx - 1 > 0)      { double d = gx - (double)(cx - 1) * 3.75; if (d < m) m = d; }
    if (cx + 1 < NC - 1) { double d = (double)(cx + 2) * 3.75 - gx; if (d < m) m = d; }
    if (cy - 1 > 0)      { double d = gy - (double)(cy - 1) * 3.75; if (d < m) m = d; }
    if (cy + 1 < NC - 1) { double d = (double)(cy + 2) * 3.75 - gy; if (d < m) m = d; }
    if (cz - 1 > 0)      { double d = gz - (double)(cz - 1) * 3.75; if (d < m) m = d; }
    if (cz + 1 < NC - 1) { double d = (double)(cz + 2) * 3.75 - gz; if (d < m) m = d; }
    if (m < 0.0) m = 0.0;
    const double m2eff = (m < 1e299) ? m * m * (1.0 - 1e-12) : 1e300;

    // two lanes per cell: lane t covers cell t>>1, slots (t&1)*8 .. +8
    int cnt = 0, base = 0;
    if (t < 54) {
        const int cell = t >> 1, h = t & 1;
        const int dx = cell / 9 - 1, dy = (cell / 3) % 3 - 1, dz = cell % 3 - 1;
        const int X = cx + dx, Y = cy + dy, Z = cz + dz;
        if (X >= 0 && X < NC && Y >= 0 && Y < NC && Z >= 0 && Z < NC) {
            const int cid = (X * NC + Y) * NC + Z;
            int c = ccnt[cid]; if (c > CAP) c = CAP;
            const int lo = h * 8;
            const int hi = (c < lo + 8) ? c : (lo + 8);
            cnt = (hi > lo) ? (hi - lo) : 0;
            base = cid * CAP + lo;
        }
    }

    // one parallel load round: up to 8 independent scell loads per lane
    double d2v[8]; int sv[8]; bool okv[8];
#pragma unroll
    for (int i = 0; i < 8; ++i) {
        okv[i] = false; d2v[i] = 0.0; sv[i] = 0;
        if (i < cnt) {
            const float4 cd = scell[base + i];
            const double ddx = gx - (double)cd.x;
            const double ddy = gy - (double)cd.y;
            const double ddz = gz - (double)cd.z;
            const double d2 = ddx * ddx + ddy * ddy + ddz * ddz;
            if (d2 < m2eff) { okv[i] = true; d2v[i] = d2; sv[i] = __float_as_int(cd.w); }
        }
    }
    int myc = 0;
#pragma unroll
    for (int i = 0; i < 8; ++i) myc += okv[i] ? 1 : 0;

    int incl = myc;
    for (int d = 1; d < 64; d <<= 1) {
        int v = __shfl_up(incl, d);
        if (t >= d) incl += v;
    }
    int total = __shfl(incl, 63);
    int pos = incl - myc;
#pragma unroll
    for (int i = 0; i < 8; ++i) {
        if (okv[i]) {
            if (pos < SURV) { skey[pos] = d2v[i]; ssid[pos] = sv[i]; }
            ++pos;
        }
    }

    // overflow points (few; usually zero)
    for (int i0 = 0; i0 < novf; i0 += 64) {
        const int i = i0 + t;
        bool act = (i < novf);
        double d2 = 0.0; int sidx = 0;
        if (act) {
            const float4 cd = ovf[i];
            const double ddx = gx - (double)cd.x;
            const double ddy = gy - (double)cd.y;
            const double ddz = gz - (double)cd.z;
            d2 = ddx * ddx + ddy * ddy + ddz * ddz;
            sidx = __float_as_int(cd.w);
            act = (d2 < m2eff);
        }
        const unsigned long long b = __ballot(act);
        const int p2 = total + (int)__popcll(b & ((1ull << t) - 1ull));
        if (act && p2 < SURV) { skey[p2] = d2; ssid[p2] = sidx; }
        total += (int)__popcll(b);
    }

    if (total < KK || total > SURV) return false;
    __syncthreads();
    rank_emit(g, total, skey, ssid, idx_out, w_out);
    return true;
}

// ---------------------------------------------------------------------------
// MEDIUM exact kNN (R=2 cube, runs for the rare sparse nodes): same
// threshold-compact-rank structure on the 5x5x5 cube with its own a-priori
// boundary threshold (m >= 7.5). Same exactness argument.
// ---------------------------------------------------------------------------
__device__ bool knn_r2(int g, int bf, const void* pos_g,
                       const int* __restrict__ ccnt,
                       const float4* __restrict__ scell,
                       const float4* __restrict__ ovf, int novf,
                       int* __restrict__ idx_out, float* __restrict__ w_out,
                       double* skey, int* ssid)
{
    const int t = threadIdx.x;

    const float gxf = ldIn(pos_g, 3 * g + 0, bf);
    const float gyf = ldIn(pos_g, 3 * g + 1, bf);
    const float gzf = ldIn(pos_g, 3 * g + 2, bf);
    const double gx = (double)gxf, gy = (double)gyf, gz = (double)gzf;
    const int cx = cellOf(gxf), cy = cellOf(gyf), cz = cellOf(gzf);

    double m = 1e300;
    if (cx - 2 > 0)      { double d = gx - (double)(cx - 2) * 3.75; if (d < m) m = d; }
    if (cx + 2 < NC - 1) { double d = (double)(cx + 3) * 3.75 - gx; if (d < m) m = d; }
    if (cy - 2 > 0)      { double d = gy - (double)(cy - 2) * 3.75; if (d < m) m = d; }
    if (cy + 2 < NC - 1) { double d = (double)(cy + 3) * 3.75 - gy; if (d < m) m = d; }
    if (cz - 2 > 0)      { double d = gz - (double)(cz - 2) * 3.75; if (d < m) m = d; }
    if (cz + 2 < NC - 1) { double d = (double)(cz + 3) * 3.75 - gz; if (d < m) m = d; }
    if (m < 0.0) m = 0.0;
    const double m2eff = (m < 1e299) ? m * m * (1.0 - 1e-12) : 1e300;

    int total = 0;
    for (int c0 = 0; c0 < 125; c0 += 64) {
        const int ci = c0 + t;
        int cnt = 0, base = 0;
        if (ci < 125) {
            const int dx = ci / 25 - 2, dy = (ci / 5) % 5 - 2, dz = ci % 5 - 2;
            const int X = cx + dx, Y = cy + dy, Z = cz + dz;
            if (X >= 0 && X < NC && Y >= 0 && Y < NC && Z >= 0 && Z < NC) {
                const int cid = (X * NC + Y) * NC + Z;
                int c = ccnt[cid]; if (c > CAP) c = CAP;
                cnt = c; base = cid * CAP;
            }
        }
        for (int i = 0; i < CAP; ++i) {
            bool act = (i < cnt);
            double d2 = 0.0; int sidx = 0;
            if (act) {
                const float4 cd = scell[base + i];
                const double ddx = gx - (double)cd.x;
                const double ddy = gy - (double)cd.y;
                const double ddz = gz - (double)cd.z;
                d2 = ddx * ddx + ddy * ddy + ddz * ddz;
                sidx = __float_as_int(cd.w);
                act = (d2 < m2eff);
            }
            const unsigned long long b = __ballot(act);
            const int p2 = total + (int)__popcll(b & ((1ull << t) - 1ull));
            if (act && p2 < SURV) { skey[p2] = d2; ssid[p2] = sidx; }
            total += (int)__popcll(b);
        }
    }
    for (int i0 = 0; i0 < novf; i0 += 64) {
        const int i = i0 + t;
        bool act = (i < novf);
        double d2 = 0.0; int sidx = 0;
        if (act) {
            const float4 cd = ovf[i];
            const double ddx = gx - (double)cd.x;
            const double ddy = gy - (double)cd.y;
            const double ddz = gz - (double)cd.z;
            d2 = ddx * ddx + ddy * ddy + ddz * ddz;
            sidx = __float_as_int(cd.w);
            act = (d2 < m2eff);
        }
        const unsigned long long b = __ballot(act);
        const int p2 = total + (int)__popcll(b & ((1ull << t) - 1ull));
        if (act && p2 < SURV) { skey[p2] = d2; ssid[p2] = sidx; }
        total += (int)__popcll(b);
    }

    if (total < KK || total > SURV) return false;
    __syncthreads();
    rank_emit(g, total, skey, ssid, idx_out, w_out);
    return true;
}

// ---------------------------------------------------------------------------
// SLOW exact kNN (last resort, ~never): round-13 proven shell-expansion.
// ---------------------------------------------------------------------------
__device__ void knn_node(int g, int bf, const void* pos_g,
                         const int* __restrict__ ccnt,
                         const float4* __restrict__ scell,
                         const float4* __restrict__ ovf, int novf,
                         int* __restrict__ idx_out, float* __restrict__ w_out,
                         unsigned short* map16, int* s_base, int* s_pref,
                         double* g_key, int* g_sid)
{
    const int t = threadIdx.x;

    const float gxf = ldIn(pos_g, 3 * g + 0, bf);
    const float gyf = ldIn(pos_g, 3 * g + 1, bf);
    const float gzf = ldIn(pos_g, 3 * g + 2, bf);
    const double gx = (double)gxf, gy = (double)gyf, gz = (double)gzf;
    const int cx = cellOf(gxf), cy = cellOf(gyf), cz = cellOf(gzf);

    double bk[KK]; int bi[KK];
#pragma unroll
    for (int j = 0; j < KK; ++j) { bk[j] = 1e300; bi[j] = 0x7fffffff; }

    for (int i = t; i < novf; i += 64) {
        const float4 cd = ovf[i];
        const double ddx = gx - (double)cd.x, ddy = gy - (double)cd.y, ddz = gz - (double)cd.z;
        const double d2 = ddx * ddx + ddy * ddy + ddz * ddz;
        const int sidx = __float_as_int(cd.w);
        if (d2 > bk[KK - 1] || (d2 == bk[KK - 1] && sidx > bi[KK - 1])) continue;
        double ck = d2; int ci2 = sidx;
#pragma unroll
        for (int j = 0; j < KK; ++j) {
            const bool less = (ck < bk[j]) || (ck == bk[j] && ci2 < bi[j]);
            const double nk = less ? ck : bk[j]; const int ni = less ? ci2 : bi[j];
            const double ok = less ? bk[j] : ck; const int oi = less ? bi[j] : ci2;
            bk[j] = nk; bi[j] = ni; ck = ok; ci2 = oi;
        }
    }

    double gk15 = 1e300;
    for (int R = 1; R <= NC; ++R) {
        const int S = 2 * R + 1;
        const int Scells = S * S * S;
        for (int cb = 0; cb < Scells; cb += 64) {
            const int ci = cb + t;
            int cnt = 0, base = 0;
            if (ci < Scells) {
                const int dz = ci % S - R;
                const int dy = (ci / S) % S - R;
                const int dx = ci / (S * S) - R;
                int ax = dx < 0 ? -dx : dx, ay = dy < 0 ? -dy : dy, az = dz < 0 ? -dz : dz;
                int cheb = ax > ay ? ax : ay; if (az > cheb) cheb = az;
                const bool want = (R == 1) ? true : (cheb == R);
                const int X = cx + dx, Y = cy + dy, Z = cz + dz;
                if (want && X >= 0 && X < NC && Y >= 0 && Y < NC && Z >= 0 && Z < NC) {
                    double m2c = 0.0;
                    {
                        const double lo = (double)X * 3.75, hi = lo + 3.75;
                        const double d = (gx < lo) ? (lo - gx) : ((gx > hi) ? (gx - hi) : 0.0);
                        m2c += d * d;
                    }
                    {
                        const double lo = (double)Y * 3.75, hi = lo + 3.75;
                        const double d = (gy < lo) ? (lo - gy) : ((gy > hi) ? (gy - hi) : 0.0);
                        m2c += d * d;
                    }
                    {
                        const double lo = (double)Z * 3.75, hi = lo + 3.75;
                        const double d = (gz < lo) ? (lo - gz) : ((gz > hi) ? (gz - hi) : 0.0);
                        m2c += d * d;
                    }
                    if (m2c <= gk15 * (1.0 + 1e-9) + 1e-300) {
                        const int cid = (X * NC + Y) * NC + Z;
                        int c = ccnt[cid]; if (c > CAP) c = CAP;
                        cnt = c; base = cid * CAP;
                    }
                }
            }
            int incl = cnt;
            for (int d = 1; d < 64; d <<= 1) {
                int v = __shfl_up(incl, d);
                if (t >= d) incl += v;
            }
            const int total = __shfl(incl, 63);
            const int pref = incl - cnt;
            s_base[t] = base; s_pref[t] = pref;
            for (int i = 0; i < cnt; ++i) map16[pref + i] = (unsigned short)t;
            __syncthreads();
            for (int pos = t; pos < total; pos += 64) {
                const int slot = map16[pos];
                const float4 cd = scell[s_base[slot] + (pos - s_pref[slot])];
                const double ddx = gx - (double)cd.x;
                const double ddy = gy - (double)cd.y;
                const double ddz = gz - (double)cd.z;
                const double d2 = ddx * ddx + ddy * ddy + ddz * ddz;
                const int sidx = __float_as_int(cd.w);
                if (d2 > bk[KK - 1]) continue;
                if (d2 == bk[KK - 1] && sidx > bi[KK - 1]) continue;
                double ck = d2; int ci2 = sidx;
#pragma unroll
                for (int j = 0; j < KK; ++j) {
                    const bool less = (ck < bk[j]) || (ck == bk[j] && ci2 < bi[j]);
                    const double nk = less ? ck : bk[j]; const int ni = less ? ci2 : bi[j];
                    const double ok = less ? bk[j] : ck; const int oi = less ? bi[j] : ci2;
                    bk[j] = nk; bi[j] = ni; ck = ok; ci2 = oi;
                }
            }
            __syncthreads();
        }
        for (int p = 0; p < KK; ++p) {
            double key = bk[0]; int sid = bi[0];
            for (int d = 1; d < 64; d <<= 1) {
                const double ok = __shfl_xor(key, d);
                const int    os = __shfl_xor(sid, d);
                if (ok < key || (ok == key && os < sid)) { key = ok; sid = os; }
            }
            if (t == 0) { g_key[p] = key; g_sid[p] = sid; }
            const bool win = (bk[0] == key) && (bi[0] == sid);
            if (win) {
#pragma unroll
                for (int j = 0; j < KK - 1; ++j) { bk[j] = bk[j + 1]; bi[j] = bi[j + 1]; }
                bk[KK - 1] = 1e300; bi[KK - 1] = 0x7fffffff;
            }
        }
        __syncthreads();
        gk15 = g_key[KK - 1];
        if (t == 0) {
#pragma unroll
            for (int j = 0; j < KK; ++j) { bk[j] = g_key[j]; bi[j] = g_sid[j]; }
        } else {
#pragma unroll
            for (int j = 0; j < KK; ++j) { bk[j] = 1e300; bi[j] = 0x7fffffff; }
        }
        __syncthreads();
        double m = 1e300;
        if (cx - R > 0)      { double d = gx - (double)(cx - R) * 3.75; if (d < m) m = d; }
        if (cx + R < NC - 1) { double d = (double)(cx + R + 1) * 3.75 - gx; if (d < m) m = d; }
        if (cy - R > 0)      { double d = gy - (double)(cy - R) * 3.75; if (d < m) m = d; }
        if (cy + R < NC - 1) { double d = (double)(cy + R + 1) * 3.75 - gy; if (d < m) m = d; }
        if (cz - R > 0)      { double d = gz - (double)(cz - R) * 3.75; if (d < m) m = d; }
        if (cz + R < NC - 1) { double d = (double)(cz + R + 1) * 3.75 - gz; if (d < m) m = d; }
        if (m < 0.0) m = 0.0;
        const double m2 = m * m * (1.0 - 1e-12);
        if (gk15 < m2) break;
    }

    if (t == 0) {
        for (int p = 0; p < KK; ++p) {
            idx_out[g * KK + p] = g_sid[p];
            w_out[g * KK + p] = expf((float)(-g_key[p]) * (1.0f / 12.5f));
        }
    }
}

// ---- MFMA helpers -------------------------------------------------------
__device__ __forceinline__ v8s loadA_bf16(const unsigned short* p) {
    return *(const v8s*)p;
}
__device__ __forceinline__ v8s loadA_f32v(const float* f) {
    const float4 a = *(const float4*)f;
    const float4 b = *(const float4*)(f + 4);
    v8s r;
    r[0] = (short)f2bf(a.x); r[1] = (short)f2bf(a.y);
    r[2] = (short)f2bf(a.z); r[3] = (short)f2bf(a.w);
    r[4] = (short)f2bf(b.x); r[5] = (short)f2bf(b.y);
    r[6] = (short)f2bf(b.z); r[7] = (short)f2bf(b.w);
    return r;
}
__device__ __forceinline__ v8s loadA_raw(const void* A, size_t off, int bf) {
    if (bf) return loadA_bf16((const unsigned short*)A + off);
    return loadA_f32v((const float*)A + off);
}

// pre tile, ONE WAVE: 16 rows x 128 cols, K=128. s-tiles also zero xs_agg slice.
__device__ void pre_tile16(int task, int bf, const void* xs, const void* xg,
                           const unsigned short* __restrict__ wpk_ps,
                           const unsigned short* __restrict__ wpk_pg,
                           unsigned short* __restrict__ hsb,
                           unsigned short* __restrict__ hgb,
                           float* __restrict__ xs_agg)
{
    const void* A; const unsigned short* wpk; unsigned short* outp; int M, m0;
    const bool is_s = (task < NBS16);
    if (is_s) { A = xs; wpk = wpk_ps; outp = hsb; M = N_S; m0 = task * 16; }
    else      { A = xg; wpk = wpk_pg; outp = hgb; M = N_G; m0 = (task - NBS16) * 16; }

    const int lane = threadIdx.x;         // 0..63
    const int q = lane >> 4, lm = lane & 15;
    const int mrow = m0 + lm;
    const bool valid = (mrow < M);

    v4f acc[8];
#pragma unroll
    for (int t = 0; t < 8; ++t) acc[t] = {0.f, 0.f, 0.f, 0.f};
    for (int ks = 0; ks < 4; ++ks) {
        v8s a = {0,0,0,0,0,0,0,0};
        if (valid) a = loadA_raw(A, (size_t)mrow * 128 + ks * 32 + q * 8, bf);
        const unsigned short* wb = wpk + (size_t)(ks * 4 + q) * 128 * 8;
#pragma unroll
        for (int t = 0; t < 8; ++t) {
            const v8s bfr = *(const v8s*)(wb + (t * 16 + lm) * 8);
            acc[t] = __builtin_amdgcn_mfma_f32_16x16x32_bf16(a, bfr, acc[t], 0, 0, 0);
        }
    }
#pragma unroll
    for (int t = 0; t < 8; ++t)
#pragma unroll
        for (int r = 0; r < 4; ++r) {
            const int row = m0 + q * 4 + r;
            if (row < M) outp[(size_t)row * 128 + t * 16 + lm] = f2bf(acc[t][r]);
        }
    if (is_s) {
        float4* dst = (float4*)(xs_agg + (size_t)m0 * 128);
        const float4 z = make_float4(0.f, 0.f, 0.f, 0.f);
        for (int i = lane; i < 16 * 32; i += 64) dst[i] = z;
    }
}

// post tile: 64 rows x 128 cols, K=256, 256 threads (4 waves).
__device__ void post_tile(int task, int bf,
                          const unsigned short* __restrict__ hsb,
                          const float* __restrict__ xs_agg,
                          const unsigned short* __restrict__ hgb,
                          const unsigned short* __restrict__ aggg,
                          const unsigned short* __restrict__ wpk_cs,
                          const unsigned short* __restrict__ wpk_cg,
                          void* out)
{
    const unsigned short* A1; const void* A2; int a2f32; const unsigned short* wpk;
    int M, m0, ooff;
    if (task < NBS) { A1 = hsb; A2 = xs_agg; a2f32 = 1; wpk = wpk_cs; M = N_S; m0 = task * 64; ooff = 0; }
    else { A1 = hgb; A2 = aggg; a2f32 = 0; wpk = wpk_cg; M = N_G; m0 = (task - NBS) * 64; ooff = N_S * DD; }

    const int wave = threadIdx.x >> 6, lane = threadIdx.x & 63;
    const int q = lane >> 4, lm = lane & 15;
    const int mb = m0 + wave * 16;
    const int mrow = mb + lm;
    const bool valid = (mrow < M);

    v4f acc[8];
#pragma unroll
    for (int t = 0; t < 8; ++t) acc[t] = {0.f, 0.f, 0.f, 0.f};
    for (int ks = 0; ks < 8; ++ks) {
        const int kk = ks * 32 + q * 8;
        v8s a = {0,0,0,0,0,0,0,0};
        if (valid) {
            if (kk < 128)      a = loadA_bf16(A1 + (size_t)mrow * 128 + kk);
            else if (a2f32)    a = loadA_f32v((const float*)A2 + (size_t)mrow * 128 + (kk - 128));
            else               a = loadA_bf16((const unsigned short*)A2 + (size_t)mrow * 128 + (kk - 128));
        }
        const unsigned short* wb = wpk + (size_t)(ks * 4 + q) * 128 * 8;
#pragma unroll
        for (int t = 0; t < 8; ++t) {
            const v8s bfr = *(const v8s*)(wb + (t * 16 + lm) * 8);
            acc[t] = __builtin_amdgcn_mfma_f32_16x16x32_bf16(a, bfr, acc[t], 0, 0, 0);
        }
    }
#pragma unroll
    for (int t = 0; t < 8; ++t)
#pragma unroll
        for (int r = 0; r < 4; ++r) {
            const int row = mb + q * 4 + r;
            if (row < M) {
                float v = acc[t][r];
                if (v < 0.f) v = 0.f;
                stOut(out, ooff + row * DD + t * 16 + lm, v, bf);
            }
        }
}

// ---------------------------------------------------------------------------
// Dispatch 2: blocks 0..117 bin surface points; blocks 118..501 pack weights.
// ---------------------------------------------------------------------------
__global__ __launch_bounds__(256) void fill_pack_kernel(
    const void* pos_s, const void* pos_g,
    const void* Wsp, const void* Wgp, const void* Wgs, const void* Wsg,
    const void* Wspost, const void* Wgpost,
    int* __restrict__ ccnt, float4* __restrict__ scell,
    float4* __restrict__ ovf, int* __restrict__ novf,
    unsigned short* __restrict__ wpk_ps, unsigned short* __restrict__ wpk_pg,
    unsigned short* __restrict__ wpk_cs, unsigned short* __restrict__ wpk_cg)
{
    const int bf = detectFlag(pos_g);
    const int bid = blockIdx.x, tid = threadIdx.x;
    if (bid < FILL_BLOCKS) {
        const int p = bid * 256 + tid;
        if (p < N_S) {
            const float x = ldIn(pos_s, 3 * p + 0, bf);
            const float y = ldIn(pos_s, 3 * p + 1, bf);
            const float z = ldIn(pos_s, 3 * p + 2, bf);
            const int cid = (cellOf(x) * NC + cellOf(y)) * NC + cellOf(z);
            const int slot = atomicAdd(&ccnt[cid], 1);
            const float4 pt = make_float4(x, y, z, __int_as_float(p));
            if (slot < CAP) scell[cid * CAP + slot] = pt;
            else            ovf[atomicAdd(novf, 1)] = pt;
        }
        return;
    }
    __shared__ float rows[256];
    const int rt = bid - FILL_BLOCKS;            // 0..383
    const int half = tid >> 7, j = tid & 127;
    const int task = rt * 2 + half;              // 0..767; branch uniform per block
    float v; unsigned short* dst; int k;
    if (task < 128) { k = task; v = ldIn(Wsp, k * DD + j, bf); dst = wpk_ps; }
    else if (task < 256) { k = task - 128; v = ldIn(Wgp, k * DD + j, bf); dst = wpk_pg; }
    else {
        const int which_g = (task >= 512);
        const int r = which_g ? (task - 512) : (task - 256);
        const void* W1 = which_g ? Wsg : Wgs;
        const void* Wp = which_g ? Wgpost : Wspost;
        dst = which_g ? wpk_cg : wpk_cs;
        k = r;
        if (r < 128) v = ldIn(Wp, r * DD + j, bf);
        else {
            rows[half * 128 + j] = ldIn(W1, (r - 128) * DD + j, bf);
            __syncthreads();
            float acc = 0.f;
            for (int m = 0; m < DD; ++m)
                acc += rows[half * 128 + m] * ldIn(Wp, (DD + m) * DD + j, bf);
            v = acc;
        }
    }
    const int ks = k >> 5, q = (k >> 3) & 3, i = k & 7;
    dst[((ks * 4 + q) * 128 + j) * 8 + i] = f2bf(v);
}

// ---------------------------------------------------------------------------
// Dispatch 3 (64-thread blocks): blocks 0..2999 = kNN (fast -> medium ->
// last-resort slow); blocks 3000..5062 = one-wave MFMA pre tiles.
// ---------------------------------------------------------------------------
__global__ __launch_bounds__(64) void knn_pre_kernel(
    const void* xs, const void* xg, const void* pos_g,
    const int* __restrict__ ccnt, const float4* __restrict__ scell,
    const float4* __restrict__ ovf, const int* __restrict__ novf,
    int* __restrict__ idx, float* __restrict__ w,
    const unsigned short* __restrict__ wpk_ps,
    const unsigned short* __restrict__ wpk_pg,
    unsigned short* __restrict__ hsb, unsigned short* __restrict__ hgb,
    float* __restrict__ xs_agg)
{
    const int bf = detectFlag(pos_g);
    const int bid = blockIdx.x;
    if (bid < KNN_BLOCKS) {
        __shared__ double skey[SURV];
        __shared__ int    ssid[SURV];
        const int nov = *novf;
        if (!knn_fast(bid, bf, pos_g, ccnt, scell, ovf, nov, idx, w, skey, ssid)) {
            __syncthreads();
            if (!knn_r2(bid, bf, pos_g, ccnt, scell, ovf, nov, idx, w, skey, ssid)) {
                __shared__ unsigned short map16[64 * CAP];
                __shared__ int s_base[64];
                __shared__ int s_pref[64];
                __shared__ double g_key[KK];
                __shared__ int g_sid[KK];
                __syncthreads();
                knn_node(bid, bf, pos_g, ccnt, scell, ovf, nov, idx, w,
                         map16, s_base, s_pref, g_key, g_sid);
            }
        }
    } else {
        pre_tile16(bid - KNN_BLOCKS, bf, xs, xg, wpk_ps, wpk_pg, hsb, hgb, xs_agg);
    }
}

// Dispatch 4: 3000 blocks x 256; lower half scatters, upper half gathers (same node).
__global__ __launch_bounds__(256) void scatgath_kernel(
    const unsigned short* __restrict__ hsb, const unsigned short* __restrict__ hgb,
    const int* __restrict__ idx, const float* __restrict__ w,
    float* __restrict__ xs_agg, unsigned short* __restrict__ aggg)
{
    const int g = blockIdx.x;
    const int half = threadIdx.x >> 7, j = threadIdx.x & 127;
    if (half == 0) {
        const float m = bf2f(hgb[g * DD + j]);
#pragma unroll
        for (int k = 0; k < KK; ++k)
            atomicAdd(&xs_agg[(size_t)idx[g * KK + k] * DD + j], m * w[g * KK + k]);
    } else {
        float acc = 0.f;
#pragma unroll
        for (int k = 0; k < KK; ++k)
            acc += w[g * KK + k] * bf2f(hsb[(size_t)idx[g * KK + k] * DD + j]);
        aggg[g * DD + j] = f2bf(acc);
    }
}

// Dispatch 5: post GEMMs, one 64-row tile per block.
__global__ __launch_bounds__(256) void mfma_post_kernel(
    const void* pos_g,
    const unsigned short* __restrict__ hsb, const float* __restrict__ xs_agg,
    const unsigned short* __restrict__ hgb, const unsigned short* __restrict__ aggg,
    const unsigned short* __restrict__ wpk_cs, const unsigned short* __restrict__ wpk_cg,
    void* out)
{
    const int bf = detectFlag(pos_g);
    post_tile(blockIdx.x, bf, hsb, xs_agg, hgb, aggg, wpk_cs, wpk_cg, out);
}

extern "C" void kernel_launch(void* const* d_in, const int* in_sizes, int n_in,
                              void* d_out, int out_size, void* d_ws, size_t ws_size,
                              hipStream_t stream)
{
    const void* xs       = d_in[0];
    const void* xg       = d_in[1];
    const void* pos_s    = d_in[2];
    const void* pos_g    = d_in[3];
    const void* W_s_pre  = d_in[4];
    const void* W_g_pre  = d_in[5];
    const void* W_gs     = d_in[6];
    const void* W_sg     = d_in[7];
    const void* W_s_post = d_in[8];
    const void* W_g_post = d_in[9];
    (void)in_sizes; (void)n_in; (void)out_size; (void)ws_size;

    char* ws = (char*)d_ws;
    size_t off_b = 0;
    auto alloc = [&](size_t bytes) -> void* {
        void* p = ws + off_b;
        off_b = (off_b + bytes + 255) & ~((size_t)255);
        return p;
    };
    unsigned short* hsb    = (unsigned short*)alloc((size_t)N_S * DD * 2);
    unsigned short* hgb    = (unsigned short*)alloc((size_t)N_G * DD * 2);
    unsigned short* aggg   = (unsigned short*)alloc((size_t)N_G * DD * 2);
    float*          xs_agg = (float*) alloc((size_t)N_S * DD * 4);
    unsigned short* wpk_ps = (unsigned short*)alloc((size_t)DD * DD * 2);
    unsigned short* wpk_pg = (unsigned short*)alloc((size_t)DD * DD * 2);
    unsigned short* wpk_cs = (unsigned short*)alloc((size_t)2 * DD * DD * 2);
    unsigned short* wpk_cg = (unsigned short*)alloc((size_t)2 * DD * DD * 2);
    int*            idx    = (int*)   alloc((size_t)NE * 4);
    float*          w      = (float*) alloc((size_t)NE * 4);
    int*            ccnt   = (int*)   alloc((size_t)CELLS * 4 + 4);  // +novf word
    int*            novf   = ccnt + CELLS;
    float4*         scell  = (float4*)alloc((size_t)CELLS * CAP * 16);
    float4*         ovf    = (float4*)alloc((size_t)N_S * 16);

    hipMemsetAsync(ccnt, 0, (size_t)CELLS * 4 + 4, stream);

    fill_pack_kernel<<<FILL_BLOCKS + PACK_BLOCKS, 256, 0, stream>>>(
        pos_s, pos_g, W_s_pre, W_g_pre, W_gs, W_sg, W_s_post, W_g_post,
        ccnt, scell, ovf, novf, wpk_ps, wpk_pg, wpk_cs, wpk_cg);

    knn_pre_kernel<<<KNN_BLOCKS + PRE_TILES, 64, 0, stream>>>(
        xs, xg, pos_g, ccnt, scell, ovf, novf, idx, w,
        wpk_ps, wpk_pg, hsb, hgb, xs_agg);

    scatgath_kernel<<<N_G, 256, 0, stream>>>(hsb, hgb, idx, w,
                                             xs_agg, aggg);

    mfma_post_kernel<<<NTILE, 256, 0, stream>>>(pos_g, hsb, xs_agg, hgb, aggg,
                                                wpk_cs, wpk_cg, d_out);
}

// Round 17
// 187.034 us; speedup vs baseline: 1.2161x; 1.2161x over previous
//
#include <hip/hip_runtime.h>
#include <stdint.h>

#define N_S 30000
#define N_G 3000
#define DD  128
#define KK  16
#define NE  (N_G * KK)
#define NC  16            // cells per axis
#define CELLS (NC * NC * NC)
#define CH  3.75f         // cell size (60/16), exactly representable
#define CAP 16            // slots per cell; overflow list keeps exactness
#define SURV 192          // survivor buffer capacity

#define FILL_BLOCKS 118   // ceil(30000/256)
#define PACK_BLOCKS 384   // 768 weight-row tasks, 2 per block
#define KNN_BLOCKS  3000  // one 64-thr block per graph node
#define NBS16 1875        // 30000/16 pre tiles (s)
#define NBG16 188         // ceil(3000/16) pre tiles (g)
#define PRE_TILES (NBS16 + NBG16)   // 2063
#define NBS 469           // ceil(30000/64) post tiles (s)
#define NBG 47            // ceil(3000/64) post tiles (g)
#define NTILE (NBS + NBG) // 516

using v8s = __attribute__((ext_vector_type(8))) short;   // 8 bf16 (4 VGPRs)
using v4f = __attribute__((ext_vector_type(4))) float;   // MFMA accumulator

__device__ __forceinline__ float bf2f(unsigned short u) {
    union { unsigned int i; float f; } v; v.i = ((unsigned int)u) << 16; return v.f;
}
__device__ __forceinline__ unsigned short f2bf(float f) {
    union { float f; unsigned int i; } v; v.f = f;
    unsigned int x = v.i;
    return (unsigned short)((x + 0x7fffu + ((x >> 16) & 1u)) >> 16);
}
__device__ __forceinline__ float ldIn(const void* p, int i, int bf) {
    return bf ? bf2f(((const unsigned short*)p)[i]) : ((const float*)p)[i];
}
__device__ __forceinline__ void stOut(void* p, int i, float v, int bf) {
    if (bf) ((unsigned short*)p)[i] = f2bf(v);
    else    ((float*)p)[i] = v;
}
__device__ __forceinline__ int cellOf(float x) {
    int c = (int)(x * (1.0f / CH));
    if (c < 0) c = 0; if (c > NC - 1) c = NC - 1;
    return c;
}

// Inline dtype probe: 16 u32 words of pos_g; bf16 low-halves in [0.25,64) put
// (w>>8)&0xFF in [0x3E,0x42]; f32 mantissa bytes ~uniform (0-1 votes of 16).
__device__ __forceinline__ int detectFlag(const void* pos_g) {
    const unsigned int* w = (const unsigned int*)pos_g;
    int votes = 0;
#pragma unroll
    for (int i = 0; i < 16; ++i) {
        const unsigned int b = (w[i] >> 8) & 0xFFu;
        votes += (b >= 0x3Eu && b <= 0x42u) ? 1 : 0;
    }
    return votes >= 8;
}

// ---------------------------------------------------------------------------
// FAST exact kNN (common path): threshold m2 known from geometry BEFORE the
// scan (m >= 3.75 A). Two lanes per cell (54 active); each lane's <=8 loads
// issue independently (one vmcnt round), survivors compacted to LDS via a
// single wave prefix-scan (buffer order irrelevant: ranks computed from
// values, (d2,idx) is a total order). If survivor count >= 16, the true
// top-16 are exactly the survivors with global lex-rank < 16.
// Returns false (rare) -> slow path.
// ---------------------------------------------------------------------------
__device__ bool knn_fast(int g, int bf, const void* pos_g,
                         const int* __restrict__ ccnt,
                         const float4* __restrict__ scell,
                         const float4* __restrict__ ovf, int novf,
                         int* __restrict__ idx_out, float* __restrict__ w_out,
                         double* skey, int* ssid)
{
    const int t = threadIdx.x;   // 0..63

    const float gxf = ldIn(pos_g, 3 * g + 0, bf);
    const float gyf = ldIn(pos_g, 3 * g + 1, bf);
    const float gzf = ldIn(pos_g, 3 * g + 2, bf);
    const double gx = (double)gxf, gy = (double)gyf, gz = (double)gzf;
    const int cx = cellOf(gxf), cy = cellOf(gyf), cz = cellOf(gzf);

    // m = min distance from query to the boundary of the R=1 examined region
    // (unclipped faces only); always >= 3.75 by construction.
    double m = 1e300;
    if (cx - 1 > 0)      { double d = gx - (double)(cx - 1) * 3.75; if (d < m) m = d; }
    if (cx + 1 < NC - 1) { double d = (double)(cx + 2) * 3.75 - gx; if (d < m) m = d; }
    if (cy - 1 > 0)      { double d = gy - (double)(cy - 1) * 3.75; if (d < m) m = d; }
    if (cy + 1 < NC - 1) { double d = (double)(cy + 2) * 3.75 - gy; if (d < m) m = d; }
    if (cz - 1 > 0)      { double d = gz - (double)(cz - 1) * 3.75; if (d < m) m = d; }
    if (cz + 1 < NC - 1) { double d = (double)(cz + 2) * 3.75 - gz; if (d < m) m = d; }
    if (m < 0.0) m = 0.0;
    const double m2eff = (m < 1e299) ? m * m * (1.0 - 1e-12) : 1e300;

    // two lanes per cell: lane t covers cell t>>1, slots (t&1)*8 .. +8
    int cnt = 0, base = 0;
    if (t < 54) {
        const int cell = t >> 1, h = t & 1;
        const int dx = cell / 9 - 1, dy = (cell / 3) % 3 - 1, dz = cell % 3 - 1;
        const int X = cx + dx, Y = cy + dy, Z = cz + dz;
        if (X >= 0 && X < NC && Y >= 0 && Y < NC && Z >= 0 && Z < NC) {
            const int cid = (X * NC + Y) * NC + Z;
            int c = ccnt[cid]; if (c > CAP) c = CAP;
            const int lo = h * 8;
            const int hi = (c < lo + 8) ? c : (lo + 8);
            cnt = (hi > lo) ? (hi - lo) : 0;
            base = cid * CAP + lo;
        }
    }

    // one parallel load round: up to 8 independent scell loads per lane
    double d2v[8]; int sv[8]; bool okv[8];
#pragma unroll
    for (int i = 0; i < 8; ++i) {
        okv[i] = false; d2v[i] = 0.0; sv[i] = 0;
        if (i < cnt) {
            const float4 cd = scell[base + i];
            const double ddx = gx - (double)cd.x;
            const double ddy = gy - (double)cd.y;
            const double ddz = gz - (double)cd.z;
            const double d2 = ddx * ddx + ddy * ddy + ddz * ddz;
            if (d2 < m2eff) { okv[i] = true; d2v[i] = d2; sv[i] = __float_as_int(cd.w); }
        }
    }
    int myc = 0;
#pragma unroll
    for (int i = 0; i < 8; ++i) myc += okv[i] ? 1 : 0;

    // wave exclusive scan of myc -> write offsets
    int incl = myc;
    for (int d = 1; d < 64; d <<= 1) {
        int v = __shfl_up(incl, d);
        if (t >= d) incl += v;
    }
    int total = __shfl(incl, 63);
    int pos = incl - myc;
#pragma unroll
    for (int i = 0; i < 8; ++i) {
        if (okv[i]) {
            if (pos < SURV) { skey[pos] = d2v[i]; ssid[pos] = sv[i]; }
            ++pos;
        }
    }

    // overflow points (few; usually zero)
    for (int i0 = 0; i0 < novf; i0 += 64) {
        const int i = i0 + t;
        bool act = (i < novf);
        double d2 = 0.0; int sidx = 0;
        if (act) {
            const float4 cd = ovf[i];
            const double ddx = gx - (double)cd.x;
            const double ddy = gy - (double)cd.y;
            const double ddz = gz - (double)cd.z;
            d2 = ddx * ddx + ddy * ddy + ddz * ddz;
            sidx = __float_as_int(cd.w);
            act = (d2 < m2eff);
        }
        const unsigned long long b = __ballot(act);
        const int p2 = total + (int)__popcll(b & ((1ull << t) - 1ull));
        if (act && p2 < SURV) { skey[p2] = d2; ssid[p2] = sidx; }
        total += (int)__popcll(b);
    }

    if (total < KK || total > SURV) return false;   // rare -> slow path
    __syncthreads();

    // exact global ranks: survivor i vs all j (lex (key, sid) order).
    // skey[j]/ssid[j] reads are wave-uniform -> LDS broadcast, no conflicts.
    const int n = total;
    double ki[3]; int si[3]; int rk[3]; int nv = 0;
    for (int i = t; i < n && nv < 3; i += 64) {
        ki[nv] = skey[i]; si[nv] = ssid[i]; rk[nv] = 0; ++nv;
    }
    for (int j = 0; j < n; ++j) {
        const double kj = skey[j]; const int sj = ssid[j];
#pragma unroll
        for (int q = 0; q < 3; ++q)
            if (q < nv)
                rk[q] += ((kj < ki[q]) || (kj == ki[q] && sj < si[q])) ? 1 : 0;
    }
#pragma unroll
    for (int q = 0; q < 3; ++q) {
        if (q < nv && rk[q] < KK) {
            idx_out[g * KK + rk[q]] = si[q];
            w_out[g * KK + rk[q]] = expf((float)(-ki[q]) * (1.0f / 12.5f));
        }
    }
    return true;
}

// ---------------------------------------------------------------------------
// SLOW exact kNN (rare path): round-13 proven shell-expansion with balanced
// LDS map, pruning, and destructive wave merges.
// ---------------------------------------------------------------------------
__device__ void knn_node(int g, int bf, const void* pos_g,
                         const int* __restrict__ ccnt,
                         const float4* __restrict__ scell,
                         const float4* __restrict__ ovf, int novf,
                         int* __restrict__ idx_out, float* __restrict__ w_out,
                         unsigned short* map16, int* s_base, int* s_pref,
                         double* g_key, int* g_sid)
{
    const int t = threadIdx.x;   // 0..63

    const float gxf = ldIn(pos_g, 3 * g + 0, bf);
    const float gyf = ldIn(pos_g, 3 * g + 1, bf);
    const float gzf = ldIn(pos_g, 3 * g + 2, bf);
    const double gx = (double)gxf, gy = (double)gyf, gz = (double)gzf;
    const int cx = cellOf(gxf), cy = cellOf(gyf), cz = cellOf(gzf);

    double bk[KK]; int bi[KK];
#pragma unroll
    for (int j = 0; j < KK; ++j) { bk[j] = 1e300; bi[j] = 0x7fffffff; }

    for (int i = t; i < novf; i += 64) {
        const float4 cd = ovf[i];
        const double ddx = gx - (double)cd.x, ddy = gy - (double)cd.y, ddz = gz - (double)cd.z;
        const double d2 = ddx * ddx + ddy * ddy + ddz * ddz;
        const int sidx = __float_as_int(cd.w);
        if (d2 > bk[KK - 1] || (d2 == bk[KK - 1] && sidx > bi[KK - 1])) continue;
        double ck = d2; int ci2 = sidx;
#pragma unroll
        for (int j = 0; j < KK; ++j) {
            const bool less = (ck < bk[j]) || (ck == bk[j] && ci2 < bi[j]);
            const double nk = less ? ck : bk[j]; const int ni = less ? ci2 : bi[j];
            const double ok = less ? bk[j] : ck; const int oi = less ? bi[j] : ci2;
            bk[j] = nk; bi[j] = ni; ck = ok; ci2 = oi;
        }
    }

    double gk15 = 1e300;
    for (int R = 1; R <= NC; ++R) {
        const int S = 2 * R + 1;
        const int Scells = S * S * S;
        for (int cb = 0; cb < Scells; cb += 64) {
            const int ci = cb + t;
            int cnt = 0, base = 0;
            if (ci < Scells) {
                const int dz = ci % S - R;
                const int dy = (ci / S) % S - R;
                const int dx = ci / (S * S) - R;
                int ax = dx < 0 ? -dx : dx, ay = dy < 0 ? -dy : dy, az = dz < 0 ? -dz : dz;
                int cheb = ax > ay ? ax : ay; if (az > cheb) cheb = az;
                const bool want = (R == 1) ? true : (cheb == R);
                const int X = cx + dx, Y = cy + dy, Z = cz + dz;
                if (want && X >= 0 && X < NC && Y >= 0 && Y < NC && Z >= 0 && Z < NC) {
                    double m2c = 0.0;
                    {
                        const double lo = (double)X * 3.75, hi = lo + 3.75;
                        const double d = (gx < lo) ? (lo - gx) : ((gx > hi) ? (gx - hi) : 0.0);
                        m2c += d * d;
                    }
                    {
                        const double lo = (double)Y * 3.75, hi = lo + 3.75;
                        const double d = (gy < lo) ? (lo - gy) : ((gy > hi) ? (gy - hi) : 0.0);
                        m2c += d * d;
                    }
                    {
                        const double lo = (double)Z * 3.75, hi = lo + 3.75;
                        const double d = (gz < lo) ? (lo - gz) : ((gz > hi) ? (gz - hi) : 0.0);
                        m2c += d * d;
                    }
                    if (m2c <= gk15 * (1.0 + 1e-9) + 1e-300) {
                        const int cid = (X * NC + Y) * NC + Z;
                        int c = ccnt[cid]; if (c > CAP) c = CAP;
                        cnt = c; base = cid * CAP;
                    }
                }
            }
            int incl = cnt;
            for (int d = 1; d < 64; d <<= 1) {
                int v = __shfl_up(incl, d);
                if (t >= d) incl += v;
            }
            const int total = __shfl(incl, 63);
            const int pref = incl - cnt;
            s_base[t] = base; s_pref[t] = pref;
            for (int i = 0; i < cnt; ++i) map16[pref + i] = (unsigned short)t;
            __syncthreads();
            for (int pos = t; pos < total; pos += 64) {
                const int slot = map16[pos];
                const float4 cd = scell[s_base[slot] + (pos - s_pref[slot])];
                const double ddx = gx - (double)cd.x;
                const double ddy = gy - (double)cd.y;
                const double ddz = gz - (double)cd.z;
                const double d2 = ddx * ddx + ddy * ddy + ddz * ddz;
                const int sidx = __float_as_int(cd.w);
                if (d2 > bk[KK - 1]) continue;
                if (d2 == bk[KK - 1] && sidx > bi[KK - 1]) continue;
                double ck = d2; int ci2 = sidx;
#pragma unroll
                for (int j = 0; j < KK; ++j) {
                    const bool less = (ck < bk[j]) || (ck == bk[j] && ci2 < bi[j]);
                    const double nk = less ? ck : bk[j]; const int ni = less ? ci2 : bi[j];
                    const double ok = less ? bk[j] : ck; const int oi = less ? bi[j] : ci2;
                    bk[j] = nk; bi[j] = ni; ck = ok; ci2 = oi;
                }
            }
            __syncthreads();
        }
        for (int p = 0; p < KK; ++p) {
            double key = bk[0]; int sid = bi[0];
            for (int d = 1; d < 64; d <<= 1) {
                const double ok = __shfl_xor(key, d);
                const int    os = __shfl_xor(sid, d);
                if (ok < key || (ok == key && os < sid)) { key = ok; sid = os; }
            }
            if (t == 0) { g_key[p] = key; g_sid[p] = sid; }
            const bool win = (bk[0] == key) && (bi[0] == sid);
            if (win) {
#pragma unroll
                for (int j = 0; j < KK - 1; ++j) { bk[j] = bk[j + 1]; bi[j] = bi[j + 1]; }
                bk[KK - 1] = 1e300; bi[KK - 1] = 0x7fffffff;
            }
        }
        __syncthreads();
        gk15 = g_key[KK - 1];
        if (t == 0) {
#pragma unroll
            for (int j = 0; j < KK; ++j) { bk[j] = g_key[j]; bi[j] = g_sid[j]; }
        } else {
#pragma unroll
            for (int j = 0; j < KK; ++j) { bk[j] = 1e300; bi[j] = 0x7fffffff; }
        }
        __syncthreads();
        double m = 1e300;
        if (cx - R > 0)      { double d = gx - (double)(cx - R) * 3.75; if (d < m) m = d; }
        if (cx + R < NC - 1) { double d = (double)(cx + R + 1) * 3.75 - gx; if (d < m) m = d; }
        if (cy - R > 0)      { double d = gy - (double)(cy - R) * 3.75; if (d < m) m = d; }
        if (cy + R < NC - 1) { double d = (double)(cy + R + 1) * 3.75 - gy; if (d < m) m = d; }
        if (cz - R > 0)      { double d = gz - (double)(cz - R) * 3.75; if (d < m) m = d; }
        if (cz + R < NC - 1) { double d = (double)(cz + R + 1) * 3.75 - gz; if (d < m) m = d; }
        if (m < 0.0) m = 0.0;
        const double m2 = m * m * (1.0 - 1e-12);
        if (gk15 < m2) break;
    }

    if (t == 0) {
        for (int p = 0; p < KK; ++p) {
            idx_out[g * KK + p] = g_sid[p];
            w_out[g * KK + p] = expf((float)(-g_key[p]) * (1.0f / 12.5f));
        }
    }
}

// ---- MFMA helpers -------------------------------------------------------
__device__ __forceinline__ v8s loadA_bf16(const unsigned short* p) {
    return *(const v8s*)p;
}
__device__ __forceinline__ v8s loadA_f32v(const float* f) {
    const float4 a = *(const float4*)f;
    const float4 b = *(const float4*)(f + 4);
    v8s r;
    r[0] = (short)f2bf(a.x); r[1] = (short)f2bf(a.y);
    r[2] = (short)f2bf(a.z); r[3] = (short)f2bf(a.w);
    r[4] = (short)f2bf(b.x); r[5] = (short)f2bf(b.y);
    r[6] = (short)f2bf(b.z); r[7] = (short)f2bf(b.w);
    return r;
}
__device__ __forceinline__ v8s loadA_raw(const void* A, size_t off, int bf) {
    if (bf) return loadA_bf16((const unsigned short*)A + off);
    return loadA_f32v((const float*)A + off);
}

// pre tile, ONE WAVE: 16 rows x 128 cols, K=128. s-tiles also zero xs_agg slice.
__device__ void pre_tile16(int task, int bf, const void* xs, const void* xg,
                           const unsigned short* __restrict__ wpk_ps,
                           const unsigned short* __restrict__ wpk_pg,
                           unsigned short* __restrict__ hsb,
                           unsigned short* __restrict__ hgb,
                           float* __restrict__ xs_agg)
{
    const void* A; const unsigned short* wpk; unsigned short* outp; int M, m0;
    const bool is_s = (task < NBS16);
    if (is_s) { A = xs; wpk = wpk_ps; outp = hsb; M = N_S; m0 = task * 16; }
    else      { A = xg; wpk = wpk_pg; outp = hgb; M = N_G; m0 = (task - NBS16) * 16; }

    const int lane = threadIdx.x;         // 0..63
    const int q = lane >> 4, lm = lane & 15;
    const int mrow = m0 + lm;
    const bool valid = (mrow < M);

    v4f acc[8];
#pragma unroll
    for (int t = 0; t < 8; ++t) acc[t] = {0.f, 0.f, 0.f, 0.f};
    for (int ks = 0; ks < 4; ++ks) {
        v8s a = {0,0,0,0,0,0,0,0};
        if (valid) a = loadA_raw(A, (size_t)mrow * 128 + ks * 32 + q * 8, bf);
        const unsigned short* wb = wpk + (size_t)(ks * 4 + q) * 128 * 8;
#pragma unroll
        for (int t = 0; t < 8; ++t) {
            const v8s bfr = *(const v8s*)(wb + (t * 16 + lm) * 8);
            acc[t] = __builtin_amdgcn_mfma_f32_16x16x32_bf16(a, bfr, acc[t], 0, 0, 0);
        }
    }
#pragma unroll
    for (int t = 0; t < 8; ++t)
#pragma unroll
        for (int r = 0; r < 4; ++r) {
            const int row = m0 + q * 4 + r;
            if (row < M) outp[(size_t)row * 128 + t * 16 + lm] = f2bf(acc[t][r]);
        }
    if (is_s) {
        float4* dst = (float4*)(xs_agg + (size_t)m0 * 128);
        const float4 z = make_float4(0.f, 0.f, 0.f, 0.f);
        for (int i = lane; i < 16 * 32; i += 64) dst[i] = z;
    }
}

// post tile: 64 rows x 128 cols, K=256, 256 threads (4 waves).
__device__ void post_tile(int task, int bf,
                          const unsigned short* __restrict__ hsb,
                          const float* __restrict__ xs_agg,
                          const unsigned short* __restrict__ hgb,
                          const unsigned short* __restrict__ aggg,
                          const unsigned short* __restrict__ wpk_cs,
                          const unsigned short* __restrict__ wpk_cg,
                          void* out)
{
    const unsigned short* A1; const void* A2; int a2f32; const unsigned short* wpk;
    int M, m0, ooff;
    if (task < NBS) { A1 = hsb; A2 = xs_agg; a2f32 = 1; wpk = wpk_cs; M = N_S; m0 = task * 64; ooff = 0; }
    else { A1 = hgb; A2 = aggg; a2f32 = 0; wpk = wpk_cg; M = N_G; m0 = (task - NBS) * 64; ooff = N_S * DD; }

    const int wave = threadIdx.x >> 6, lane = threadIdx.x & 63;
    const int q = lane >> 4, lm = lane & 15;
    const int mb = m0 + wave * 16;
    const int mrow = mb + lm;
    const bool valid = (mrow < M);

    v4f acc[8];
#pragma unroll
    for (int t = 0; t < 8; ++t) acc[t] = {0.f, 0.f, 0.f, 0.f};
    for (int ks = 0; ks < 8; ++ks) {
        const int kk = ks * 32 + q * 8;
        v8s a = {0,0,0,0,0,0,0,0};
        if (valid) {
            if (kk < 128)      a = loadA_bf16(A1 + (size_t)mrow * 128 + kk);
            else if (a2f32)    a = loadA_f32v((const float*)A2 + (size_t)mrow * 128 + (kk - 128));
            else               a = loadA_bf16((const unsigned short*)A2 + (size_t)mrow * 128 + (kk - 128));
        }
        const unsigned short* wb = wpk + (size_t)(ks * 4 + q) * 128 * 8;
#pragma unroll
        for (int t = 0; t < 8; ++t) {
            const v8s bfr = *(const v8s*)(wb + (t * 16 + lm) * 8);
            acc[t] = __builtin_amdgcn_mfma_f32_16x16x32_bf16(a, bfr, acc[t], 0, 0, 0);
        }
    }
#pragma unroll
    for (int t = 0; t < 8; ++t)
#pragma unroll
        for (int r = 0; r < 4; ++r) {
            const int row = mb + q * 4 + r;
            if (row < M) {
                float v = acc[t][r];
                if (v < 0.f) v = 0.f;
                stOut(out, ooff + row * DD + t * 16 + lm, v, bf);
            }
        }
}

// ---------------------------------------------------------------------------
// Dispatch 2: blocks 0..117 bin surface points; blocks 118..501 pack weights.
// ---------------------------------------------------------------------------
__global__ __launch_bounds__(256) void fill_pack_kernel(
    const void* pos_s, const void* pos_g,
    const void* Wsp, const void* Wgp, const void* Wgs, const void* Wsg,
    const void* Wspost, const void* Wgpost,
    int* __restrict__ ccnt, float4* __restrict__ scell,
    float4* __restrict__ ovf, int* __restrict__ novf,
    unsigned short* __restrict__ wpk_ps, unsigned short* __restrict__ wpk_pg,
    unsigned short* __restrict__ wpk_cs, unsigned short* __restrict__ wpk_cg)
{
    const int bf = detectFlag(pos_g);
    const int bid = blockIdx.x, tid = threadIdx.x;
    if (bid < FILL_BLOCKS) {
        const int p = bid * 256 + tid;
        if (p < N_S) {
            const float x = ldIn(pos_s, 3 * p + 0, bf);
            const float y = ldIn(pos_s, 3 * p + 1, bf);
            const float z = ldIn(pos_s, 3 * p + 2, bf);
            const int cid = (cellOf(x) * NC + cellOf(y)) * NC + cellOf(z);
            const int slot = atomicAdd(&ccnt[cid], 1);
            const float4 pt = make_float4(x, y, z, __int_as_float(p));
            if (slot < CAP) scell[cid * CAP + slot] = pt;
            else            ovf[atomicAdd(novf, 1)] = pt;
        }
        return;
    }
    __shared__ float rows[256];
    const int rt = bid - FILL_BLOCKS;            // 0..383
    const int half = tid >> 7, j = tid & 127;
    const int task = rt * 2 + half;              // 0..767; branch uniform per block
    float v; unsigned short* dst; int k;
    if (task < 128) { k = task; v = ldIn(Wsp, k * DD + j, bf); dst = wpk_ps; }
    else if (task < 256) { k = task - 128; v = ldIn(Wgp, k * DD + j, bf); dst = wpk_pg; }
    else {
        const int which_g = (task >= 512);
        const int r = which_g ? (task - 512) : (task - 256);
        const void* W1 = which_g ? Wsg : Wgs;
        const void* Wp = which_g ? Wgpost : Wspost;
        dst = which_g ? wpk_cg : wpk_cs;
        k = r;
        if (r < 128) v = ldIn(Wp, r * DD + j, bf);
        else {
            rows[half * 128 + j] = ldIn(W1, (r - 128) * DD + j, bf);
            __syncthreads();
            float acc = 0.f;
            for (int m = 0; m < DD; ++m)
                acc += rows[half * 128 + m] * ldIn(Wp, (DD + m) * DD + j, bf);
            v = acc;
        }
    }
    const int ks = k >> 5, q = (k >> 3) & 3, i = k & 7;
    dst[((ks * 4 + q) * 128 + j) * 8 + i] = f2bf(v);
}

// ---------------------------------------------------------------------------
// Dispatch 3 (64-thread blocks): blocks 0..2999 = kNN (fast path + rare slow
// fallback); blocks 3000..5062 = one-wave MFMA pre tiles.
// ---------------------------------------------------------------------------
__global__ __launch_bounds__(64) void knn_pre_kernel(
    const void* xs, const void* xg, const void* pos_g,
    const int* __restrict__ ccnt, const float4* __restrict__ scell,
    const float4* __restrict__ ovf, const int* __restrict__ novf,
    int* __restrict__ idx, float* __restrict__ w,
    const unsigned short* __restrict__ wpk_ps,
    const unsigned short* __restrict__ wpk_pg,
    unsigned short* __restrict__ hsb, unsigned short* __restrict__ hgb,
    float* __restrict__ xs_agg)
{
    const int bf = detectFlag(pos_g);
    const int bid = blockIdx.x;
    if (bid < KNN_BLOCKS) {
        __shared__ double skey[SURV];
        __shared__ int    ssid[SURV];
        const int nov = *novf;
        if (!knn_fast(bid, bf, pos_g, ccnt, scell, ovf, nov, idx, w, skey, ssid)) {
            __shared__ unsigned short map16[64 * CAP];
            __shared__ int s_base[64];
            __shared__ int s_pref[64];
            __shared__ double g_key[KK];
            __shared__ int g_sid[KK];
            __syncthreads();
            knn_node(bid, bf, pos_g, ccnt, scell, ovf, nov, idx, w,
                     map16, s_base, s_pref, g_key, g_sid);
        }
    } else {
        pre_tile16(bid - KNN_BLOCKS, bf, xs, xg, wpk_ps, wpk_pg, hsb, hgb, xs_agg);
    }
}

// Dispatch 4: 3000 blocks x 256; lower half scatters, upper half gathers (same node).
__global__ __launch_bounds__(256) void scatgath_kernel(
    const unsigned short* __restrict__ hsb, const unsigned short* __restrict__ hgb,
    const int* __restrict__ idx, const float* __restrict__ w,
    float* __restrict__ xs_agg, unsigned short* __restrict__ aggg)
{
    const int g = blockIdx.x;
    const int half = threadIdx.x >> 7, j = threadIdx.x & 127;
    if (half == 0) {
        const float m = bf2f(hgb[g * DD + j]);
#pragma unroll
        for (int k = 0; k < KK; ++k)
            atomicAdd(&xs_agg[(size_t)idx[g * KK + k] * DD + j], m * w[g * KK + k]);
    } else {
        float acc = 0.f;
#pragma unroll
        for (int k = 0; k < KK; ++k)
            acc += w[g * KK + k] * bf2f(hsb[(size_t)idx[g * KK + k] * DD + j]);
        aggg[g * DD + j] = f2bf(acc);
    }
}

// Dispatch 5: post GEMMs, one 64-row tile per block.
__global__ __launch_bounds__(256) void mfma_post_kernel(
    const void* pos_g,
    const unsigned short* __restrict__ hsb, const float* __restrict__ xs_agg,
    const unsigned short* __restrict__ hgb, const unsigned short* __restrict__ aggg,
    const unsigned short* __restrict__ wpk_cs, const unsigned short* __restrict__ wpk_cg,
    void* out)
{
    const int bf = detectFlag(pos_g);
    post_tile(blockIdx.x, bf, hsb, xs_agg, hgb, aggg, wpk_cs, wpk_cg, out);
}

extern "C" void kernel_launch(void* const* d_in, const int* in_sizes, int n_in,
                              void* d_out, int out_size, void* d_ws, size_t ws_size,
                              hipStream_t stream)
{
    const void* xs       = d_in[0];
    const void* xg       = d_in[1];
    const void* pos_s    = d_in[2];
    const void* pos_g    = d_in[3];
    const void* W_s_pre  = d_in[4];
    const void* W_g_pre  = d_in[5];
    const void* W_gs     = d_in[6];
    const void* W_sg     = d_in[7];
    const void* W_s_post = d_in[8];
    const void* W_g_post = d_in[9];
    (void)in_sizes; (void)n_in; (void)out_size; (void)ws_size;

    char* ws = (char*)d_ws;
    size_t off_b = 0;
    auto alloc = [&](size_t bytes) -> void* {
        void* p = ws + off_b;
        off_b = (off_b + bytes + 255) & ~((size_t)255);
        return p;
    };
    unsigned short* hsb    = (unsigned short*)alloc((size_t)N_S * DD * 2);
    unsigned short* hgb    = (unsigned short*)alloc((size_t)N_G * DD * 2);
    unsigned short* aggg   = (unsigned short*)alloc((size_t)N_G * DD * 2);
    float*          xs_agg = (float*) alloc((size_t)N_S * DD * 4);
    unsigned short* wpk_ps = (unsigned short*)alloc((size_t)DD * DD * 2);
    unsigned short* wpk_pg = (unsigned short*)alloc((size_t)DD * DD * 2);
    unsigned short* wpk_cs = (unsigned short*)alloc((size_t)2 * DD * DD * 2);
    unsigned short* wpk_cg = (unsigned short*)alloc((size_t)2 * DD * DD * 2);
    int*            idx    = (int*)   alloc((size_t)NE * 4);
    float*          w      = (float*) alloc((size_t)NE * 4);
    int*            ccnt   = (int*)   alloc((size_t)CELLS * 4 + 4);  // +novf word
    int*            novf   = ccnt + CELLS;
    float4*         scell  = (float4*)alloc((size_t)CELLS * CAP * 16);
    float4*         ovf    = (float4*)alloc((size_t)N_S * 16);

    hipMemsetAsync(ccnt, 0, (size_t)CELLS * 4 + 4, stream);

    fill_pack_kernel<<<FILL_BLOCKS + PACK_BLOCKS, 256, 0, stream>>>(
        pos_s, pos_g, W_s_pre, W_g_pre, W_gs, W_sg, W_s_post, W_g_post,
        ccnt, scell, ovf, novf, wpk_ps, wpk_pg, wpk_cs, wpk_cg);

    knn_pre_kernel<<<KNN_BLOCKS + PRE_TILES, 64, 0, stream>>>(
        xs, xg, pos_g, ccnt, scell, ovf, novf, idx, w,
        wpk_ps, wpk_pg, hsb, hgb, xs_agg);

    scatgath_kernel<<<N_G, 256, 0, stream>>>(hsb, hgb, idx, w,
                                             xs_agg, aggg);

    mfma_post_kernel<<<NTILE, 256, 0, stream>>>(pos_g, hsb, xs_agg, hgb, aggg,
                                                wpk_cs, wpk_cg, d_out);
}